// Round 1
// baseline (192.773 us; speedup 1.0000x reference)
//
#include <hip/hip_runtime.h>

#define KSZ  121
#define KMEAN 60
#define IMW  512
#define IMH  512
#define NPLANES 24   // 8 * 3

// ---------------------------------------------------------------------------
// Kernel 1: compute normalized 1D Gaussian weights (121 taps, padded to 124
// with zeros so the horizontal pass can read aligned float4 tap groups).
// 2D kernel = w1d (outer) w1d since the 1/(2*pi*var) prefactor cancels in
// the normalization: gk2d = (g (x) g) / (sum g)^2.
// ---------------------------------------------------------------------------
__global__ void weights_kernel(const float* __restrict__ sigma,
                               float* __restrict__ wout) {
    __shared__ float g[128];
    __shared__ float ssum;
    int t = threadIdx.x;
    float s = sigma[0] * 8.0f + 16.0f;
    float var = s * s;
    float val = 0.0f;
    if (t < KSZ) {
        float d = (float)t - (float)KMEAN;
        val = expf(-(d * d) / (2.0f * var));
    }
    g[t] = val;
    __syncthreads();
    if (t == 0) {
        float sum = 0.0f;
        for (int i = 0; i < KSZ; ++i) sum += g[i];
        ssum = sum;
    }
    __syncthreads();
    float inv = 1.0f / ssum;
    if (t < 124) wout[t] = (t < KSZ) ? val * inv : 0.0f;
}

// ---------------------------------------------------------------------------
// Kernel 2: horizontal pass. One block per image row. Row is staged into LDS
// pre-padded with the clamped halo (srow[i] = x[clamp(i-60)]), so the compute
// loop does aligned float4 LDS reads only. Each thread produces 4 consecutive
// outputs via a register sliding window: 31 ds_read_b128 + 496 FMA per thread.
// ---------------------------------------------------------------------------
__global__ __launch_bounds__(128) void hblur(const float* __restrict__ x,
                                             const float* __restrict__ wts,
                                             float* __restrict__ tmp) {
    __shared__ __align__(16) float srow[640];   // 512 + 120 halo, padded to 640
    __shared__ __align__(16) float wt[124];
    const int row = blockIdx.x;                 // 0..12287 (plane*512 + r)
    const int t   = threadIdx.x;                // 0..127

    const float* __restrict__ xr = x + (size_t)row * IMW;
    for (int i = t; i < 640; i += 128) {
        int j = i - KMEAN;
        j = min(max(j, 0), IMW - 1);
        srow[i] = xr[j];
    }
    if (t < 124) wt[t] = wts[t];
    __syncthreads();

    const float4* __restrict__ win = reinterpret_cast<const float4*>(srow);
    const float4* __restrict__ w4  = reinterpret_cast<const float4*>(wt);

    float a0 = 0.f, a1 = 0.f, a2 = 0.f, a3 = 0.f;
    float4 cur = win[t];                        // srow[4t .. 4t+3]
    #pragma unroll
    for (int c = 0; c < 31; ++c) {              // taps 4c..4c+3 (121..123 zero)
        float4 nxt = win[t + c + 1];
        float4 wv  = w4[c];
        a0 += wv.x * cur.x + wv.y * cur.y + wv.z * cur.z + wv.w * cur.w;
        a1 += wv.x * cur.y + wv.y * cur.z + wv.z * cur.w + wv.w * nxt.x;
        a2 += wv.x * cur.z + wv.y * cur.w + wv.z * nxt.x + wv.w * nxt.y;
        a3 += wv.x * cur.w + wv.y * nxt.x + wv.z * nxt.y + wv.w * nxt.z;
        cur = nxt;
    }
    float4 r; r.x = a0; r.y = a1; r.z = a2; r.w = a3;
    reinterpret_cast<float4*>(tmp + (size_t)row * IMW)[t] = r;
}

// ---------------------------------------------------------------------------
// Kernel 3: vertical pass. Each thread computes 8 consecutive output rows of
// one column: (8+120)=128 coalesced global loads shared across 968 FMAs
// (16 loads/output instead of 121). Weight window rolls through registers
// (compiler renames the shifts away under unroll) — one LDS broadcast per k.
// ---------------------------------------------------------------------------
__global__ __launch_bounds__(256) void vblur(const float* __restrict__ tmp,
                                             const float* __restrict__ wts,
                                             float* __restrict__ out) {
    __shared__ float wt[128];
    const int t = threadIdx.x;
    if (t < 124) wt[t] = wts[t];
    __syncthreads();

    const int col   = blockIdx.x * 256 + t;
    const int r0    = blockIdx.y * 8;
    const int plane = blockIdx.z;
    const float* __restrict__ tp = tmp + (size_t)plane * (IMW * IMH);
    float* __restrict__ op       = out + (size_t)plane * (IMW * IMH);

    float a[8] = {0.f,0.f,0.f,0.f,0.f,0.f,0.f,0.f};

    // prologue: k = 0..7 (partial tap coverage, tap = k-i valid for i <= k)
    #pragma unroll
    for (int k = 0; k < 8; ++k) {
        int r = r0 - KMEAN + k;
        r = min(max(r, 0), IMH - 1);
        float v = tp[(size_t)r * IMW + col];
        #pragma unroll
        for (int i = 0; i <= k; ++i) a[i] += wt[k - i] * v;
    }

    // rolling weight window: wr[j] = wt[k-7+j]
    float wr[8];
    #pragma unroll
    for (int j = 0; j < 8; ++j) wr[j] = wt[j + 1];

    // main: k = 8..120, all 8 taps valid
    #pragma unroll 8
    for (int k = 8; k <= 120; ++k) {
        int r = r0 - KMEAN + k;
        r = min(max(r, 0), IMH - 1);
        float v = tp[(size_t)r * IMW + col];
        #pragma unroll
        for (int i = 0; i < 8; ++i) a[i] += wr[7 - i] * v;
        #pragma unroll
        for (int j = 0; j < 7; ++j) wr[j] = wr[j + 1];
        wr[7] = wt[k + 1];   // wt[121] == 0 pad, harmless on last iter
    }

    // epilogue: k = 121..127 (tap = k-i valid for i >= k-120)
    #pragma unroll
    for (int k = 121; k < 128; ++k) {
        int r = r0 - KMEAN + k;
        r = min(max(r, 0), IMH - 1);
        float v = tp[(size_t)r * IMW + col];
        #pragma unroll
        for (int i = k - 120; i < 8; ++i) a[i] += wt[k - i] * v;
    }

    #pragma unroll
    for (int i = 0; i < 8; ++i)
        op[(size_t)(r0 + i) * IMW + col] = a[i];
}

// ---------------------------------------------------------------------------
extern "C" void kernel_launch(void* const* d_in, const int* in_sizes, int n_in,
                              void* d_out, int out_size, void* d_ws, size_t ws_size,
                              hipStream_t stream) {
    const float* x     = (const float*)d_in[0];
    const float* sigma = (const float*)d_in[1];
    float* out = (float*)d_out;

    // workspace layout: [0,512) bytes = padded 1D weights, then fp32 intermediate
    float* wts = (float*)d_ws;
    float* tmp = (float*)((char*)d_ws + 512);

    weights_kernel<<<1, 128, 0, stream>>>(sigma, wts);
    hblur<<<NPLANES * IMH, 128, 0, stream>>>(x, wts, tmp);
    vblur<<<dim3(IMW / 256, IMH / 8, NPLANES), 256, 0, stream>>>(tmp, wts, out);
}

// Round 2
// 191.508 us; speedup vs baseline: 1.0066x; 1.0066x over previous
//
#include <hip/hip_runtime.h>

#define KSZ   121
#define KMEAN 60
#define IMW   512
#define IMH   512
#define NPLANES 24   // 8 * 3

// ---------------------------------------------------------------------------
// Kernel 1: normalized 1D Gaussian weights, 124 floats (121 taps + 3 zero pad)
// single wave, shuffle reduction. gk2d = outer(w1,w1) after normalization.
// ---------------------------------------------------------------------------
__global__ __launch_bounds__(64) void weights_kernel(const float* __restrict__ sigma,
                                                     float* __restrict__ wout) {
    int t = threadIdx.x;                     // 0..63
    float s = sigma[0] * 8.0f + 16.0f;
    float ninv = -1.0f / (2.0f * s * s);
    float d0 = (float)(t - KMEAN);
    float d1 = (float)(t + 64 - KMEAN);
    float v0 = __expf(d0 * d0 * ninv);
    float v1 = (t + 64 < KSZ) ? __expf(d1 * d1 * ninv) : 0.0f;
    float sum = v0 + v1;
    for (int off = 32; off; off >>= 1) sum += __shfl_xor(sum, off, 64);
    float inv = 1.0f / sum;
    wout[t] = v0 * inv;
    if (t < 60) wout[t + 64] = v1 * inv;     // covers 64..123 (121..123 are 0)
}

// ---------------------------------------------------------------------------
// Kernel 2: horizontal pass. Same proven structure as round 1 (LDS-staged
// padded row, 4 outputs/thread, 16B-stride ds_read_b128 sliding window) BUT
// weights now come from GLOBAL via uniform index -> s_load through K$.
// Zero LDS broadcast traffic. A/B probe on the bank-conflict source.
// ---------------------------------------------------------------------------
__global__ __launch_bounds__(128) void hblur(const float* __restrict__ x,
                                             const float* __restrict__ wts,
                                             float* __restrict__ tmp) {
    __shared__ __align__(16) float srow[640];   // 60 halo + 512 + 68 pad
    const int row = blockIdx.x;                 // 0..12287 (plane*512 + r)
    const int t   = threadIdx.x;                // 0..127

    const float* __restrict__ xr = x + (size_t)row * IMW;
    #pragma unroll
    for (int i = t; i < 640; i += 128) {
        int j = i - KMEAN;
        j = min(max(j, 0), IMW - 1);
        srow[i] = xr[j];
    }
    __syncthreads();

    const float4* __restrict__ win = reinterpret_cast<const float4*>(srow);
    const float4* __restrict__ w4g = reinterpret_cast<const float4*>(wts);

    float a0 = 0.f, a1 = 0.f, a2 = 0.f, a3 = 0.f;
    float4 cur = win[t];                        // srow[4t .. 4t+3]
    #pragma unroll
    for (int c = 0; c < 31; ++c) {              // taps 4c..4c+3 (121..123 zero)
        float4 nxt = win[t + c + 1];
        float4 wv  = w4g[c];                    // uniform -> scalar load (K$)
        a0 += wv.x * cur.x + wv.y * cur.y + wv.z * cur.z + wv.w * cur.w;
        a1 += wv.x * cur.y + wv.y * cur.z + wv.z * cur.w + wv.w * nxt.x;
        a2 += wv.x * cur.z + wv.y * cur.w + wv.z * nxt.x + wv.w * nxt.y;
        a3 += wv.x * cur.w + wv.y * nxt.x + wv.z * nxt.y + wv.w * nxt.z;
        cur = nxt;
    }
    float4 r; r.x = a0; r.y = a1; r.z = a2; r.w = a3;
    reinterpret_cast<float4*>(tmp + (size_t)row * IMW)[t] = r;
}

// ---------------------------------------------------------------------------
// Kernel 3: vertical pass, redesigned. Thread t owns a float4 column group
// (128 threads x float4 = 512 cols) and 8 output rows. Tap-quad loop with an
// 11-slot float4 register row-window rotated by 4 each iter; 4 fully
// coalesced 1KB/wave loads + 128 scalar FMAs per iter. Weights via scalar
// loads. No LDS, no rolling-weight v_movs.
// ---------------------------------------------------------------------------
__global__ __launch_bounds__(128) void vblur(const float* __restrict__ tmp,
                                             const float* __restrict__ wts,
                                             float* __restrict__ out) {
    const int t     = threadIdx.x;            // float4-column index 0..127
    const int r0    = blockIdx.x * 8;         // output rows r0..r0+7
    const int plane = blockIdx.y;
    const int base  = r0 - KMEAN;

    const float4* __restrict__ tp4 = reinterpret_cast<const float4*>(tmp + (size_t)plane * (IMW * IMH));
    float4*       __restrict__ op4 = reinterpret_cast<float4*>(out + (size_t)plane * (IMW * IMH));
    const float4* __restrict__ w4g = reinterpret_cast<const float4*>(wts);

    float4 W[11];
    #pragma unroll
    for (int d = 0; d < 11; ++d) {
        int r = min(max(base + d, 0), IMH - 1);
        W[d] = tp4[(size_t)r * (IMW / 4) + t];
    }

    float4 acc[8];
    #pragma unroll
    for (int i = 0; i < 8; ++i) acc[i] = make_float4(0.f, 0.f, 0.f, 0.f);

    #pragma unroll 4
    for (int c = 0; c < 31; ++c) {
        float4 wv = w4g[c];                   // uniform -> scalar load
        #pragma unroll
        for (int s = 0; s < 4; ++s) {
            float ws_ = (s == 0) ? wv.x : (s == 1) ? wv.y : (s == 2) ? wv.z : wv.w;
            #pragma unroll
            for (int i = 0; i < 8; ++i) {
                acc[i].x = fmaf(ws_, W[i + s].x, acc[i].x);
                acc[i].y = fmaf(ws_, W[i + s].y, acc[i].y);
                acc[i].z = fmaf(ws_, W[i + s].z, acc[i].z);
                acc[i].w = fmaf(ws_, W[i + s].w, acc[i].w);
            }
        }
        if (c < 30) {
            #pragma unroll
            for (int d = 0; d < 7; ++d) W[d] = W[d + 4];
            #pragma unroll
            for (int e = 0; e < 4; ++e) {
                int r = min(max(base + 4 * c + 11 + e, 0), IMH - 1);
                W[7 + e] = tp4[(size_t)r * (IMW / 4) + t];
            }
        }
    }

    #pragma unroll
    for (int i = 0; i < 8; ++i)
        op4[(size_t)(r0 + i) * (IMW / 4) + t] = acc[i];
}

// ---------------------------------------------------------------------------
extern "C" void kernel_launch(void* const* d_in, const int* in_sizes, int n_in,
                              void* d_out, int out_size, void* d_ws, size_t ws_size,
                              hipStream_t stream) {
    const float* x     = (const float*)d_in[0];
    const float* sigma = (const float*)d_in[1];
    float* out = (float*)d_out;

    // workspace: [0,512) bytes padded 1D weights, then fp32 intermediate (25MB)
    float* wts = (float*)d_ws;
    float* tmp = (float*)((char*)d_ws + 512);

    weights_kernel<<<1, 64, 0, stream>>>(sigma, wts);
    hblur<<<NPLANES * IMH, 128, 0, stream>>>(x, wts, tmp);
    vblur<<<dim3(IMH / 8, NPLANES), 128, 0, stream>>>(tmp, wts, out);
}

// Round 4
// 142.695 us; speedup vs baseline: 1.3509x; 1.3421x over previous
//
#include <hip/hip_runtime.h>

#define KSZ   121
#define KMEAN 60
#define IMW   512
#define IMH   512
#define NPLANES 24   // 8 * 3

// ---------------------------------------------------------------------------
// Kernel 1: normalized 1D Gaussian weights, 124 floats (121 taps + 3 zero pad)
// single wave, shuffle reduction. gk2d = outer(w1,w1) after normalization.
// (unchanged from round 2 — passed graph timing twice)
// ---------------------------------------------------------------------------
__global__ __launch_bounds__(64) void weights_kernel(const float* __restrict__ sigma,
                                                     float* __restrict__ wout) {
    int t = threadIdx.x;                     // 0..63
    float s = sigma[0] * 8.0f + 16.0f;
    float ninv = -1.0f / (2.0f * s * s);
    float d0 = (float)(t - KMEAN);
    float d1 = (float)(t + 64 - KMEAN);
    float v0 = __expf(d0 * d0 * ninv);
    float v1 = (t + 64 < KSZ) ? __expf(d1 * d1 * ninv) : 0.0f;
    float sum = v0 + v1;
    for (int off = 32; off; off >>= 1) sum += __shfl_xor(sum, off, 64);
    float inv = 1.0f / sum;
    wout[t] = v0 * inv;
    if (t < 60) wout[t + 64] = v1 * inv;     // covers 64..123 (121..123 are 0)
}

// Clamped quad load for the horizontal window. Window start is quad-aligned
// (60 % 4 == 0), so out-of-range quads are pure splats of the edge pixel.
__device__ __forceinline__ float4 loadq(const float4* __restrict__ xr4, int qi) {
    int j = min(max(qi, 0), (IMW / 4) - 1);
    float4 v = xr4[j];
    if (qi < 0)              { v.y = v.x; v.z = v.x; v.w = v.x; }   // all cols < 0
    if (qi > (IMW / 4) - 1)  { v.x = v.w; v.y = v.w; v.z = v.w; }   // all cols > 511
    return v;
}

// ---------------------------------------------------------------------------
// Kernel 2: horizontal pass, LDS-FREE (round-3 structure, NO XCD swizzle —
// natural block order; round 3's post-timing divergence is attributed to the
// swizzle/L2-residency interaction, so correctness never depends on block->XCD
// mapping again). Thread computes 4 consecutive outputs from a global sliding
// quad window: per tap-quad, one coalesced global_load_dwordx4 + 16 FMA;
// re-reads hit L1/L2. No LDS, no barrier, no bank conflicts.
// ---------------------------------------------------------------------------
__global__ __launch_bounds__(256) void hblur(const float* __restrict__ x,
                                             const float* __restrict__ wts,
                                             float* __restrict__ tmp) {
    const int tid = threadIdx.x;
    const int b   = blockIdx.x;                       // 0..6143 (row pairs)
    const int row = b * 2 + (tid >> 7);               // waves don't straddle rows
    const int t   = tid & 127;                        // output quad index in row

    const float4* __restrict__ xr4 = reinterpret_cast<const float4*>(x + (size_t)row * IMW);
    const float4* __restrict__ w4  = reinterpret_cast<const float4*>(wts);

    float a0 = 0.f, a1 = 0.f, a2 = 0.f, a3 = 0.f;
    float4 cur = loadq(xr4, t - 15);                  // taps 0..3 window start
    #pragma unroll
    for (int c = 0; c < 31; ++c) {                    // taps 4c..4c+3 (121..123 zero)
        float4 nxt = loadq(xr4, t - 14 + c);
        float4 wv  = w4[c];                           // uniform -> s_load (K$)
        a0 += wv.x * cur.x + wv.y * cur.y + wv.z * cur.z + wv.w * cur.w;
        a1 += wv.x * cur.y + wv.y * cur.z + wv.z * cur.w + wv.w * nxt.x;
        a2 += wv.x * cur.z + wv.y * cur.w + wv.z * nxt.x + wv.w * nxt.y;
        a3 += wv.x * cur.w + wv.y * nxt.x + wv.z * nxt.y + wv.w * nxt.z;
        cur = nxt;
    }
    float4 r; r.x = a0; r.y = a1; r.z = a2; r.w = a3;
    reinterpret_cast<float4*>(tmp + (size_t)row * IMW)[t] = r;
}

// ---------------------------------------------------------------------------
// Kernel 3: vertical pass — round-2 proven body scaled to 16 rows/thread and
// float2 column groups (256 thr = 512 cols). tmp re-read drops from 16x to
// (16+120)/16 = 8.5x -> ~214 MB total, the bandwidth-bound lever. Natural
// block order, no swizzle. ~90 VGPRs -> 3+ waves/SIMD, grid 768 blocks.
// ---------------------------------------------------------------------------
#define VROWS 16
__global__ __launch_bounds__(256) void vblur(const float* __restrict__ tmp,
                                             const float* __restrict__ out_dummy_unused,
                                             const float* __restrict__ wts,
                                             float* __restrict__ out) {
    const int t     = threadIdx.x;            // float2-column index 0..255
    const int b     = blockIdx.x;             // 0..767
    const int plane = b >> 5;                 // b / 32
    const int r0    = (b & 31) * VROWS;       // output rows r0..r0+15
    const int base  = r0 - KMEAN;

    const float2* __restrict__ tp2 = reinterpret_cast<const float2*>(tmp + (size_t)plane * (IMW * IMH));
    float2*       __restrict__ op2 = reinterpret_cast<float2*>(out + (size_t)plane * (IMW * IMH));
    const float4* __restrict__ w4g = reinterpret_cast<const float4*>(wts);

    float2 W[VROWS + 3];                      // rows base+4c .. base+4c+18
    #pragma unroll
    for (int d = 0; d < VROWS + 3; ++d) {
        int r = min(max(base + d, 0), IMH - 1);
        W[d] = tp2[(size_t)r * (IMW / 2) + t];
    }

    float2 acc[VROWS];
    #pragma unroll
    for (int i = 0; i < VROWS; ++i) acc[i] = make_float2(0.f, 0.f);

    #pragma unroll 4
    for (int c = 0; c < 31; ++c) {
        float4 wv = w4g[c];                   // uniform -> scalar load
        #pragma unroll
        for (int s = 0; s < 4; ++s) {
            float ws_ = (s == 0) ? wv.x : (s == 1) ? wv.y : (s == 2) ? wv.z : wv.w;
            #pragma unroll
            for (int i = 0; i < VROWS; ++i) {
                acc[i].x = fmaf(ws_, W[i + s].x, acc[i].x);
                acc[i].y = fmaf(ws_, W[i + s].y, acc[i].y);
            }
        }
        if (c < 30) {
            #pragma unroll
            for (int d = 0; d < VROWS - 1; ++d) W[d] = W[d + 4];
            #pragma unroll
            for (int e = 0; e < 4; ++e) {
                int r = min(max(base + 4 * c + VROWS + 3 + e, 0), IMH - 1);
                W[VROWS - 1 + e] = tp2[(size_t)r * (IMW / 2) + t];
            }
        }
    }

    #pragma unroll
    for (int i = 0; i < VROWS; ++i)
        op2[(size_t)(r0 + i) * (IMW / 2) + t] = acc[i];
}

// ---------------------------------------------------------------------------
extern "C" void kernel_launch(void* const* d_in, const int* in_sizes, int n_in,
                              void* d_out, int out_size, void* d_ws, size_t ws_size,
                              hipStream_t stream) {
    const float* x     = (const float*)d_in[0];
    const float* sigma = (const float*)d_in[1];
    float* out = (float*)d_out;

    // workspace: [0,512) bytes padded 1D weights, then fp32 intermediate (24MiB)
    float* wts = (float*)d_ws;
    float* tmp = (float*)((char*)d_ws + 512);

    weights_kernel<<<1, 64, 0, stream>>>(sigma, wts);
    hblur<<<NPLANES * IMH / 2, 256, 0, stream>>>(x, wts, tmp);
    vblur<<<NPLANES * (IMH / VROWS), 256, 0, stream>>>(tmp, nullptr, wts, out);
}

// Round 5
// 133.579 us; speedup vs baseline: 1.4431x; 1.0682x over previous
//
#include <hip/hip_runtime.h>

#define KSZ   121
#define KMEAN 60
#define IMW   512
#define IMH   512
#define NPLANES 24   // 8 * 3

typedef float f32x4 __attribute__((ext_vector_type(4)));
typedef float f32x2 __attribute__((ext_vector_type(2)));
typedef int   i32x4 __attribute__((ext_vector_type(4)));

// CK-style raw buffer intrinsics: HW bounds check returns 0 for OOB lanes.
__device__ f32x4 buf_load_x4(i32x4 srsrc, int voffset, int soffset, int aux)
    __asm("llvm.amdgcn.raw.buffer.load.v4f32");
__device__ f32x2 buf_load_x2(i32x4 srsrc, int voffset, int soffset, int aux)
    __asm("llvm.amdgcn.raw.buffer.load.v2f32");
__device__ void buf_store_x2(f32x2 data, i32x4 srsrc, int voffset, int soffset, int aux)
    __asm("llvm.amdgcn.raw.buffer.store.v2f32");

__device__ __forceinline__ i32x4 make_srd(const void* p, int bytes) {
    union { const void* p; unsigned u[2]; } a; a.p = p;
    i32x4 r;
    r.x = (int)__builtin_amdgcn_readfirstlane((int)a.u[0]);   // wave-uniform base
    r.y = (int)__builtin_amdgcn_readfirstlane((int)a.u[1]);
    r.z = bytes;          // num_records: OOB load -> 0, OOB store -> dropped
    r.w = 0x00020000;     // raw dword SRD word3 (gfx9/gfx950)
    return r;
}

// Clamp a possibly-wrapped-negative byte offset to a positive OOB value.
// Also blocks LLVM from folding the +16c into the MUBUF imm across the wrap.
__device__ __forceinline__ int safev(int voff) {
    unsigned u = (unsigned)voff;
    return (int)(u < 0x7fff0000u ? u : 0x7fff0000u);   // one v_min_u32
}

// ---------------------------------------------------------------------------
// Kernel 1: taps w[0..120] (pad to 128 with 0) + edge-correction tables.
//   out[o] = sum_k w[k]*zpad[o+k-60] + edge0*L[o] + edgeN*R[o]
//   L[o] = P[59-o] (o<=59), R[o] = 1-P[571-o] (o>=452), P = prefix sum of w.
// Same tables serve rows (vblur) and cols (hblur). ws: [0,128) taps,
// [128,640) L, [640,1152) R, tmp at float offset 1152.
// ---------------------------------------------------------------------------
__global__ __launch_bounds__(128) void weights_kernel(const float* __restrict__ sigma,
                                                      float* __restrict__ ws) {
    __shared__ float w[121];
    __shared__ float P[121];
    int t = threadIdx.x;
    float s = sigma[0] * 8.0f + 16.0f;
    float ninv = -1.0f / (2.0f * s * s);
    if (t < 121) { float d = (float)(t - KMEAN); w[t] = __expf(d * d * ninv); }
    __syncthreads();
    if (t == 0) {
        float sum = 0.f;
        for (int i = 0; i < 121; ++i) sum += w[i];
        float inv = 1.f / sum, run = 0.f;
        for (int i = 0; i < 121; ++i) { float wi = w[i] * inv; w[i] = wi; run += wi; P[i] = run; }
    }
    __syncthreads();
    ws[t] = (t < 121) ? w[t] : 0.f;                       // taps, 121..127 = 0
    #pragma unroll
    for (int j = 0; j < 4; ++j) {
        int o = t * 4 + j;
        ws[128 + o] = (o <= 59)  ? P[59 - o]          : 0.f;   // L
        ws[640 + o] = (o >= 452) ? (1.f - P[571 - o]) : 0.f;   // R
    }
}

// ---------------------------------------------------------------------------
// Kernel 2: horizontal pass. Thread -> 8 consecutive outputs (cols 8t..8t+7).
// Sliding 3-quad register window; per tap-quad: ONE buffer_load_dwordx4
// (1 v_add + 1 v_min addr cost, HW zero-fill at both row edges) + 32 FMA.
// Edge replication restored by x0*L / x511*R corrections. No LDS, no clamps.
// Wave = one row (row uniform -> SRD in SGPRs).
// ---------------------------------------------------------------------------
__global__ __launch_bounds__(256) void hblur(const float* __restrict__ x,
                                             const float* __restrict__ ws,
                                             float* __restrict__ tmp) {
    const int tid = threadIdx.x;
    const int t   = tid & 63;                       // output group: cols 8t..8t+7
    const int row = blockIdx.x * 4 + (tid >> 6);    // 4 rows (4 waves) per block

    const float* __restrict__ xr = x + (size_t)row * IMW;
    const i32x4 srd = make_srd(xr, IMW * 4);        // 2048-byte row buffer
    const f32x4* __restrict__ w4 = (const f32x4*)ws;

    const int voff = 32 * t - 240;                  // byte offset of quad (2t-15)

    float a0=0.f,a1=0.f,a2=0.f,a3=0.f,a4=0.f,a5=0.f,a6=0.f,a7=0.f;
    f32x4 Q0 = buf_load_x4(srd, safev(voff),      0, 0);
    f32x4 Q1 = buf_load_x4(srd, safev(voff + 16), 0, 0);
    #pragma unroll
    for (int c = 0; c < 31; ++c) {                  // taps 4c..4c+3 (121..123 w=0)
        f32x4 Q2 = buf_load_x4(srd, safev(voff + 32 + 16 * c), 0, 0);
        f32x4 w  = w4[c];                           // uniform -> s_load_dwordx4
        a0 += w.x*Q0.x + w.y*Q0.y + w.z*Q0.z + w.w*Q0.w;
        a1 += w.x*Q0.y + w.y*Q0.z + w.z*Q0.w + w.w*Q1.x;
        a2 += w.x*Q0.z + w.y*Q0.w + w.z*Q1.x + w.w*Q1.y;
        a3 += w.x*Q0.w + w.y*Q1.x + w.z*Q1.y + w.w*Q1.z;
        a4 += w.x*Q1.x + w.y*Q1.y + w.z*Q1.z + w.w*Q1.w;
        a5 += w.x*Q1.y + w.y*Q1.z + w.z*Q1.w + w.w*Q2.x;
        a6 += w.x*Q1.z + w.y*Q1.w + w.z*Q2.x + w.w*Q2.y;
        a7 += w.x*Q1.w + w.y*Q2.x + w.z*Q2.y + w.w*Q2.z;
        Q0 = Q1; Q1 = Q2;
    }

    // replicate-pad corrections
    const float x0 = xr[0], xN = xr[IMW - 1];
    const f32x4* __restrict__ L4 = (const f32x4*)(ws + 128);
    const f32x4* __restrict__ R4 = (const f32x4*)(ws + 640);
    f32x4 La = L4[2*t], Lb = L4[2*t+1], Ra = R4[2*t], Rb = R4[2*t+1];
    a0 += x0*La.x + xN*Ra.x;  a1 += x0*La.y + xN*Ra.y;
    a2 += x0*La.z + xN*Ra.z;  a3 += x0*La.w + xN*Ra.w;
    a4 += x0*Lb.x + xN*Rb.x;  a5 += x0*Lb.y + xN*Rb.y;
    a6 += x0*Lb.z + xN*Rb.z;  a7 += x0*Lb.w + xN*Rb.w;

    f32x4* __restrict__ o4 = (f32x4*)(tmp + (size_t)row * IMW);
    f32x4 ra; ra.x=a0; ra.y=a1; ra.z=a2; ra.w=a3;
    f32x4 rb; rb.x=a4; rb.y=a5; rb.z=a6; rb.w=a7;
    o4[2*t]     = ra;
    o4[2*t + 1] = rb;
}

// ---------------------------------------------------------------------------
// Kernel 3: vertical pass. Thread -> 16 consecutive output rows of one
// float2 column pair. All tmp loads via SRD with voffset = 8*col (constant
// VGPR) and soffset = row*2048 (SALU, wave-uniform): ZERO per-load VALU.
// Rows <0 / >511 return 0 from the HW bounds check; replicate-pad restored
// by scalar L[r]/R[r] corrections (s_loads). Stores likewise via SRD.
// 128-thr blocks, grid 1536 -> ~20+ waves/CU for latency hiding.
// ---------------------------------------------------------------------------
#define VR 16
__global__ __launch_bounds__(128) void vblur(const float* __restrict__ tmp,
                                             const float* __restrict__ ws,
                                             float* __restrict__ out) {
    const int t     = threadIdx.x;                 // 0..127
    const int b     = blockIdx.x;                  // 0..1535
    const int half  = b & 1;                       // column half
    const int r0    = ((b >> 1) & 31) * VR;        // output rows r0..r0+15
    const int plane = b >> 6;
    const int base  = r0 - KMEAN;
    const int voff  = (half * 128 + t) * 8;        // byte offset of float2 col pair

    const float* __restrict__ tp = tmp + (size_t)plane * (IMW * IMH);
    float*       __restrict__ op = out + (size_t)plane * (IMW * IMH);
    const i32x4 srdT = make_srd(tp, IMW * IMH * 4);   // 1 MiB plane buffer
    const i32x4 srdO = make_srd(op, IMW * IMH * 4);
    const f32x4* __restrict__ w4 = (const f32x4*)ws;

    f32x2 W[VR + 3];                               // rows base+4c+d
    #pragma unroll
    for (int d = 0; d < VR + 3; ++d)
        W[d] = buf_load_x2(srdT, voff, (base + d) * (IMW * 4), 0);

    f32x2 acc[VR];
    #pragma unroll
    for (int i = 0; i < VR; ++i) { acc[i].x = 0.f; acc[i].y = 0.f; }

    #pragma unroll 4
    for (int c = 0; c < 31; ++c) {
        f32x4 w = w4[c];                           // uniform -> s_load
        #pragma unroll
        for (int s = 0; s < 4; ++s) {
            float wv = (s == 0) ? w.x : (s == 1) ? w.y : (s == 2) ? w.z : w.w;
            #pragma unroll
            for (int i = 0; i < VR; ++i) {
                acc[i].x = fmaf(wv, W[i + s].x, acc[i].x);
                acc[i].y = fmaf(wv, W[i + s].y, acc[i].y);
            }
        }
        if (c < 30) {
            #pragma unroll
            for (int d = 0; d < VR - 1; ++d) W[d] = W[d + 4];
            #pragma unroll
            for (int e = 0; e < 4; ++e)
                W[VR - 1 + e] = buf_load_x2(srdT, voff, (base + 4*c + VR + 3 + e) * (IMW * 4), 0);
        }
    }

    // replicate-pad corrections: rows 0 and 511, scalar weights L[r]/R[r]
    f32x2 T0 = buf_load_x2(srdT, voff, 0, 0);
    f32x2 TN = buf_load_x2(srdT, voff, (IMH - 1) * (IMW * 4), 0);
    const float* __restrict__ Lf = ws + 128;
    const float* __restrict__ Rf = ws + 640;
    #pragma unroll
    for (int i = 0; i < VR; ++i) {
        float L = Lf[r0 + i], R = Rf[r0 + i];      // uniform -> s_load
        acc[i].x += L * T0.x + R * TN.x;
        acc[i].y += L * T0.y + R * TN.y;
    }

    #pragma unroll
    for (int i = 0; i < VR; ++i)
        buf_store_x2(acc[i], srdO, voff, (r0 + i) * (IMW * 4), 0);
}

// ---------------------------------------------------------------------------
extern "C" void kernel_launch(void* const* d_in, const int* in_sizes, int n_in,
                              void* d_out, int out_size, void* d_ws, size_t ws_size,
                              hipStream_t stream) {
    const float* x     = (const float*)d_in[0];
    const float* sigma = (const float*)d_in[1];
    float* out = (float*)d_out;

    // ws: [0,128) taps, [128,640) L, [640,1152) R, tmp at float offset 1152
    float* ws_f = (float*)d_ws;
    float* tmp  = ws_f + 1152;

    weights_kernel<<<1, 128, 0, stream>>>(sigma, ws_f);
    hblur<<<NPLANES * IMH / 4, 256, 0, stream>>>(x, ws_f, tmp);
    vblur<<<NPLANES * (IMH / VR) * 2, 128, 0, stream>>>(tmp, ws_f, out);
}

// Round 7
// 131.969 us; speedup vs baseline: 1.4607x; 1.0122x over previous
//
#include <hip/hip_runtime.h>

#define KSZ   121
#define KMEAN 60
#define IMW   512
#define IMH   512
#define NPLANES 24   // 8 * 3

typedef float f32x4 __attribute__((ext_vector_type(4)));
typedef float f32x2 __attribute__((ext_vector_type(2)));
typedef int   i32x4 __attribute__((ext_vector_type(4)));

// CK-style raw buffer intrinsics: HW bounds check returns 0 for OOB lanes.
__device__ f32x4 buf_load_x4(i32x4 srsrc, int voffset, int soffset, int aux)
    __asm("llvm.amdgcn.raw.buffer.load.v4f32");
__device__ f32x2 buf_load_x2(i32x4 srsrc, int voffset, int soffset, int aux)
    __asm("llvm.amdgcn.raw.buffer.load.v2f32");
__device__ void buf_store_x2(f32x2 data, i32x4 srsrc, int voffset, int soffset, int aux)
    __asm("llvm.amdgcn.raw.buffer.store.v2f32");

// NOTE: SRD lives in SGPRs -> every input to make_srd MUST be wave-uniform.
// Structural invariant for hblur: one row per wave (64 threads/row). Round 6
// violated this (2 rows/wave) and silently convolved odd rows with even-row
// data.
__device__ __forceinline__ i32x4 make_srd(const void* p, int bytes) {
    union { const void* p; unsigned u[2]; } a; a.p = p;
    i32x4 r;
    r.x = (int)__builtin_amdgcn_readfirstlane((int)a.u[0]);   // wave-uniform base
    r.y = (int)__builtin_amdgcn_readfirstlane((int)a.u[1]);
    r.z = bytes;          // num_records: OOB load -> 0, OOB store -> dropped
    r.w = 0x00020000;     // raw dword SRD word3 (gfx9/gfx950)
    return r;
}

// Clamp a possibly-wrapped-negative byte offset to a positive OOB value.
// Also blocks LLVM from folding imm offsets across the wrap.
__device__ __forceinline__ int safev(int voff) {
    unsigned u = (unsigned)voff;
    return (int)(u < 0x7fff0000u ? u : 0x7fff0000u);   // one v_min_u32
}

// ---------------------------------------------------------------------------
// Kernel 1: taps w[0..120] (pad to 128 with 0) + edge-correction tables.
//   out[o] = sum_k w[k]*zpad[o+k-60] + edge0*L[o] + edgeN*R[o]
//   L[o] = P[59-o] (o<=59), R[o] = 1-P[571-o] (o>=452), P = prefix sum of w.
// ws: [0,128) taps, [128,640) L, [640,1152) R, tmp at float offset 1152.
// (proven rounds 5/6-validation)
// ---------------------------------------------------------------------------
__global__ __launch_bounds__(128) void weights_kernel(const float* __restrict__ sigma,
                                                      float* __restrict__ ws) {
    __shared__ float w[121];
    __shared__ float P[121];
    int t = threadIdx.x;
    float s = sigma[0] * 8.0f + 16.0f;
    float ninv = -1.0f / (2.0f * s * s);
    if (t < 121) { float d = (float)(t - KMEAN); w[t] = __expf(d * d * ninv); }
    __syncthreads();
    if (t == 0) {
        float sum = 0.f;
        for (int i = 0; i < 121; ++i) sum += w[i];
        float inv = 1.f / sum, run = 0.f;
        for (int i = 0; i < 121; ++i) { float wi = w[i] * inv; w[i] = wi; run += wi; P[i] = run; }
    }
    __syncthreads();
    ws[t] = (t < 121) ? w[t] : 0.f;                       // taps, 121..127 = 0
    #pragma unroll
    for (int j = 0; j < 4; ++j) {
        int o = t * 4 + j;
        ws[128 + o] = (o <= 59)  ? P[59 - o]          : 0.f;   // L
        ws[640 + o] = (o >= 452) ? (1.f - P[571 - o]) : 0.f;   // R
    }
}

// ---------------------------------------------------------------------------
// Kernel 2: horizontal pass — EXACT round-5 proven version. 64 threads/row
// (one row per wave: SRD-uniformity invariant), 8 outputs/thread. Per
// tap-quad: ONE buffer_load_dwordx4 (1 v_add + 1 v_min addr cost, HW
// zero-fill at both row edges) + 32 FMA. Edge replication restored by
// x0*L / x511*R corrections. No LDS, no clamps.
// ---------------------------------------------------------------------------
__global__ __launch_bounds__(256) void hblur(const float* __restrict__ x,
                                             const float* __restrict__ ws,
                                             float* __restrict__ tmp) {
    const int tid = threadIdx.x;
    const int t   = tid & 63;                       // output group: cols 8t..8t+7
    const int row = blockIdx.x * 4 + (tid >> 6);    // 4 rows (4 waves) per block

    const float* __restrict__ xr = x + (size_t)row * IMW;
    const i32x4 srd = make_srd(xr, IMW * 4);        // 2048-byte row buffer
    const f32x4* __restrict__ w4 = (const f32x4*)ws;

    const int voff = 32 * t - 240;                  // byte offset of quad (2t-15)

    float a0=0.f,a1=0.f,a2=0.f,a3=0.f,a4=0.f,a5=0.f,a6=0.f,a7=0.f;
    f32x4 Q0 = buf_load_x4(srd, safev(voff),      0, 0);
    f32x4 Q1 = buf_load_x4(srd, safev(voff + 16), 0, 0);
    #pragma unroll
    for (int c = 0; c < 31; ++c) {                  // taps 4c..4c+3 (121..123 w=0)
        f32x4 Q2 = buf_load_x4(srd, safev(voff + 32 + 16 * c), 0, 0);
        f32x4 w  = w4[c];                           // uniform -> s_load_dwordx4
        a0 += w.x*Q0.x + w.y*Q0.y + w.z*Q0.z + w.w*Q0.w;
        a1 += w.x*Q0.y + w.y*Q0.z + w.z*Q0.w + w.w*Q1.x;
        a2 += w.x*Q0.z + w.y*Q0.w + w.z*Q1.x + w.w*Q1.y;
        a3 += w.x*Q0.w + w.y*Q1.x + w.z*Q1.y + w.w*Q1.z;
        a4 += w.x*Q1.x + w.y*Q1.y + w.z*Q1.z + w.w*Q1.w;
        a5 += w.x*Q1.y + w.y*Q1.z + w.z*Q1.w + w.w*Q2.x;
        a6 += w.x*Q1.z + w.y*Q1.w + w.z*Q2.x + w.w*Q2.y;
        a7 += w.x*Q1.w + w.y*Q2.x + w.z*Q2.y + w.w*Q2.z;
        Q0 = Q1; Q1 = Q2;
    }

    // replicate-pad corrections
    const float x0 = xr[0], xN = xr[IMW - 1];
    const f32x4* __restrict__ L4 = (const f32x4*)(ws + 128);
    const f32x4* __restrict__ R4 = (const f32x4*)(ws + 640);
    f32x4 La = L4[2*t], Lb = L4[2*t+1], Ra = R4[2*t], Rb = R4[2*t+1];
    a0 += x0*La.x + xN*Ra.x;  a1 += x0*La.y + xN*Ra.y;
    a2 += x0*La.z + xN*Ra.z;  a3 += x0*La.w + xN*Ra.w;
    a4 += x0*Lb.x + xN*Rb.x;  a5 += x0*Lb.y + xN*Rb.y;
    a6 += x0*Lb.z + xN*Rb.z;  a7 += x0*Lb.w + xN*Rb.w;

    f32x4* __restrict__ o4 = (f32x4*)(tmp + (size_t)row * IMW);
    f32x4 ra; ra.x=a0; ra.y=a1; ra.z=a2; ra.w=a3;
    f32x4 rb; rb.x=a4; rb.y=a5; rb.z=a6; rb.w=a7;
    o4[2*t]     = ra;
    o4[2*t + 1] = rb;
}

// ---------------------------------------------------------------------------
// Kernel 3: vertical pass — round-5 body + explicit 2-chunk register
// prefetch (P0/P1): refill rows are issued ~2 FMA blocks (~1000 cyc) before
// consumption, covering L2/L3 miss latency on the XCD-scattered tmp. Full
// unroll -> window rotation is pure renaming. SRD loads: voffset = col*8
// (constant VGPR), soffset = row*2048 (SALU); rows <0/>511 -> HW zero-fill,
// replicate restored by scalar L[r]/R[r] corrections.
// Invariant at iter c: W[d]=row base+4c+d (d<19), P0[e]=+19+e, P1[e]=+23+e.
// ---------------------------------------------------------------------------
#define VR 16
__global__ __launch_bounds__(128) void vblur(const float* __restrict__ tmp,
                                             const float* __restrict__ ws,
                                             float* __restrict__ out) {
    const int t     = threadIdx.x;                 // 0..127
    const int b     = blockIdx.x;                  // 0..1535
    const int half  = b & 1;                       // column half
    const int r0    = ((b >> 1) & 31) * VR;        // output rows r0..r0+15
    const int plane = b >> 6;
    const int base  = r0 - KMEAN;
    const int voff  = (half * 128 + t) * 8;        // byte offset of float2 col pair

    const float* __restrict__ tp = tmp + (size_t)plane * (IMW * IMH);
    float*       __restrict__ op = out + (size_t)plane * (IMW * IMH);
    const i32x4 srdT = make_srd(tp, IMW * IMH * 4);   // 1 MiB plane buffer
    const i32x4 srdO = make_srd(op, IMW * IMH * 4);
    const f32x4* __restrict__ w4 = (const f32x4*)ws;

    f32x2 W[VR + 3];                               // rows base+4c .. base+4c+18
    #pragma unroll
    for (int d = 0; d < VR + 3; ++d)
        W[d] = buf_load_x2(srdT, voff, (base + d) * (IMW * 4), 0);
    f32x2 P0[4], P1[4];                            // chunks c+1, c+2 in flight
    #pragma unroll
    for (int e = 0; e < 4; ++e)
        P0[e] = buf_load_x2(srdT, voff, (base + 19 + e) * (IMW * 4), 0);
    #pragma unroll
    for (int e = 0; e < 4; ++e)
        P1[e] = buf_load_x2(srdT, voff, (base + 23 + e) * (IMW * 4), 0);

    f32x2 acc[VR];
    #pragma unroll
    for (int i = 0; i < VR; ++i) { acc[i].x = 0.f; acc[i].y = 0.f; }

    #pragma unroll
    for (int c = 0; c < 31; ++c) {
        f32x4 w = w4[c];                           // uniform -> s_load
        #pragma unroll
        for (int s = 0; s < 4; ++s) {
            float wv = (s == 0) ? w.x : (s == 1) ? w.y : (s == 2) ? w.z : w.w;
            #pragma unroll
            for (int i = 0; i < VR; ++i) {
                acc[i].x = fmaf(wv, W[i + s].x, acc[i].x);
                acc[i].y = fmaf(wv, W[i + s].y, acc[i].y);
            }
        }
        if (c < 30) {
            #pragma unroll
            for (int d = 0; d < VR - 1; ++d) W[d] = W[d + 4];
            #pragma unroll
            for (int e = 0; e < 4; ++e) W[VR - 1 + e] = P0[e];
            #pragma unroll
            for (int e = 0; e < 4; ++e) P0[e] = P1[e];
            if (c < 28) {
                #pragma unroll
                for (int e = 0; e < 4; ++e)
                    P1[e] = buf_load_x2(srdT, voff, (base + 4*c + 27 + e) * (IMW * 4), 0);
            }
        }
    }

    // replicate-pad corrections: rows 0 and 511, scalar weights L[r]/R[r]
    f32x2 T0 = buf_load_x2(srdT, voff, 0, 0);
    f32x2 TN = buf_load_x2(srdT, voff, (IMH - 1) * (IMW * 4), 0);
    const float* __restrict__ Lf = ws + 128;
    const float* __restrict__ Rf = ws + 640;
    #pragma unroll
    for (int i = 0; i < VR; ++i) {
        float L = Lf[r0 + i], R = Rf[r0 + i];      // uniform -> s_load
        acc[i].x += L * T0.x + R * TN.x;
        acc[i].y += L * T0.y + R * TN.y;
    }

    #pragma unroll
    for (int i = 0; i < VR; ++i)
        buf_store_x2(acc[i], srdO, voff, (r0 + i) * (IMW * 4), 0);
}

// ---------------------------------------------------------------------------
extern "C" void kernel_launch(void* const* d_in, const int* in_sizes, int n_in,
                              void* d_out, int out_size, void* d_ws, size_t ws_size,
                              hipStream_t stream) {
    const float* x     = (const float*)d_in[0];
    const float* sigma = (const float*)d_in[1];
    float* out = (float*)d_out;

    // ws: [0,128) taps, [128,640) L, [640,1152) R, tmp at float offset 1152
    float* ws_f = (float*)d_ws;
    float* tmp  = ws_f + 1152;

    weights_kernel<<<1, 128, 0, stream>>>(sigma, ws_f);
    hblur<<<NPLANES * IMH / 4, 256, 0, stream>>>(x, ws_f, tmp);
    vblur<<<NPLANES * (IMH / VR) * 2, 128, 0, stream>>>(tmp, ws_f, out);
}

// Round 8
// 123.630 us; speedup vs baseline: 1.5593x; 1.0675x over previous
//
#include <hip/hip_runtime.h>

#define KSZ   121
#define KMEAN 60
#define IMW   512
#define IMH   512
#define NPLANES 24   // 8 * 3

typedef float    f32x4 __attribute__((ext_vector_type(4)));
typedef float    f32x2 __attribute__((ext_vector_type(2)));
typedef int      i32x4 __attribute__((ext_vector_type(4)));
typedef unsigned u32x4 __attribute__((ext_vector_type(4)));

// CK-style raw buffer intrinsics: HW bounds check returns 0 for OOB lanes.
__device__ f32x4 buf_load_x4(i32x4 srsrc, int voffset, int soffset, int aux)
    __asm("llvm.amdgcn.raw.buffer.load.v4f32");
__device__ unsigned buf_load_u32(i32x4 srsrc, int voffset, int soffset, int aux)
    __asm("llvm.amdgcn.raw.buffer.load.i32");
__device__ f32x2 buf_load_x2(i32x4 srsrc, int voffset, int soffset, int aux)
    __asm("llvm.amdgcn.raw.buffer.load.v2f32");
__device__ void buf_store_x2(f32x2 data, i32x4 srsrc, int voffset, int soffset, int aux)
    __asm("llvm.amdgcn.raw.buffer.store.v2f32");

// NOTE: SRD lives in SGPRs -> every input to make_srd MUST be wave-uniform.
// Structural invariant for hblur: one row per wave (64 threads/row).
__device__ __forceinline__ i32x4 make_srd(const void* p, int bytes) {
    union { const void* p; unsigned u[2]; } a; a.p = p;
    i32x4 r;
    r.x = (int)__builtin_amdgcn_readfirstlane((int)a.u[0]);   // wave-uniform base
    r.y = (int)__builtin_amdgcn_readfirstlane((int)a.u[1]);
    r.z = bytes;          // num_records: OOB load -> 0, OOB store -> dropped
    r.w = 0x00020000;     // raw dword SRD word3 (gfx9/gfx950)
    return r;
}

// Clamp a possibly-wrapped-negative byte offset to a positive OOB value.
__device__ __forceinline__ int safev(int voff) {
    unsigned u = (unsigned)voff;
    return (int)(u < 0x7fff0000u ? u : 0x7fff0000u);   // one v_min_u32
}

// round-to-nearest-even fp32 -> bf16 (3 VALU)
__device__ __forceinline__ unsigned bf16rne(float f) {
    unsigned u = __float_as_uint(f);
    return (u + 0x7fffu + ((u >> 16) & 1u)) >> 16;
}
__device__ __forceinline__ unsigned bf16pair(float lo, float hi) {
    return bf16rne(lo) | (bf16rne(hi) << 16);
}
// unpack dword -> 2 fp32 (2 VALU)
__device__ __forceinline__ f32x2 bf16unpk(unsigned u) {
    f32x2 r;
    r.x = __uint_as_float(u << 16);
    r.y = __uint_as_float(u & 0xffff0000u);
    return r;
}

// ---------------------------------------------------------------------------
// Kernel 1: taps w[0..120] (pad to 128 with 0) + edge-correction tables.
//   out[o] = sum_k w[k]*zpad[o+k-60] + edge0*L[o] + edgeN*R[o]
//   L[o] = P[59-o] (o<=59), R[o] = 1-P[571-o] (o>=452), P = prefix sum of w.
// ws: [0,128) taps, [128,640) L, [640,1152) R; bf16 tmp at byte 4608.
// (proven rounds 5-7)
// ---------------------------------------------------------------------------
__global__ __launch_bounds__(128) void weights_kernel(const float* __restrict__ sigma,
                                                      float* __restrict__ ws) {
    __shared__ float w[121];
    __shared__ float P[121];
    int t = threadIdx.x;
    float s = sigma[0] * 8.0f + 16.0f;
    float ninv = -1.0f / (2.0f * s * s);
    if (t < 121) { float d = (float)(t - KMEAN); w[t] = __expf(d * d * ninv); }
    __syncthreads();
    if (t == 0) {
        float sum = 0.f;
        for (int i = 0; i < 121; ++i) sum += w[i];
        float inv = 1.f / sum, run = 0.f;
        for (int i = 0; i < 121; ++i) { float wi = w[i] * inv; w[i] = wi; run += wi; P[i] = run; }
    }
    __syncthreads();
    ws[t] = (t < 121) ? w[t] : 0.f;                       // taps, 121..127 = 0
    #pragma unroll
    for (int j = 0; j < 4; ++j) {
        int o = t * 4 + j;
        ws[128 + o] = (o <= 59)  ? P[59 - o]          : 0.f;   // L
        ws[640 + o] = (o >= 452) ? (1.f - P[571 - o]) : 0.f;   // R
    }
}

// ---------------------------------------------------------------------------
// Kernel 2: horizontal pass — round-5 proven body; epilogue now RNE-packs the
// 8 fp32 outputs into 4 bf16-pair dwords (halves tmp write traffic).
// 64 threads/row (SRD-uniformity invariant), 8 outputs/thread; per tap-quad
// ONE buffer_load_dwordx4 + 32 FMA; zero-pad via SRD bounds check, replicate
// restored by x0*L / x511*R corrections.
// ---------------------------------------------------------------------------
__global__ __launch_bounds__(256) void hblur(const float* __restrict__ x,
                                             const float* __restrict__ ws,
                                             unsigned short* __restrict__ tmpb) {
    const int tid = threadIdx.x;
    const int t   = tid & 63;                       // output group: cols 8t..8t+7
    const int row = blockIdx.x * 4 + (tid >> 6);    // 4 rows (4 waves) per block

    const float* __restrict__ xr = x + (size_t)row * IMW;
    const i32x4 srd = make_srd(xr, IMW * 4);        // 2048-byte row buffer
    const f32x4* __restrict__ w4 = (const f32x4*)ws;

    const int voff = 32 * t - 240;                  // byte offset of quad (2t-15)

    float a0=0.f,a1=0.f,a2=0.f,a3=0.f,a4=0.f,a5=0.f,a6=0.f,a7=0.f;
    f32x4 Q0 = buf_load_x4(srd, safev(voff),      0, 0);
    f32x4 Q1 = buf_load_x4(srd, safev(voff + 16), 0, 0);
    #pragma unroll
    for (int c = 0; c < 31; ++c) {                  // taps 4c..4c+3 (121..123 w=0)
        f32x4 Q2 = buf_load_x4(srd, safev(voff + 32 + 16 * c), 0, 0);
        f32x4 w  = w4[c];                           // uniform -> s_load_dwordx4
        a0 += w.x*Q0.x + w.y*Q0.y + w.z*Q0.z + w.w*Q0.w;
        a1 += w.x*Q0.y + w.y*Q0.z + w.z*Q0.w + w.w*Q1.x;
        a2 += w.x*Q0.z + w.y*Q0.w + w.z*Q1.x + w.w*Q1.y;
        a3 += w.x*Q0.w + w.y*Q1.x + w.z*Q1.y + w.w*Q1.z;
        a4 += w.x*Q1.x + w.y*Q1.y + w.z*Q1.z + w.w*Q1.w;
        a5 += w.x*Q1.y + w.y*Q1.z + w.z*Q1.w + w.w*Q2.x;
        a6 += w.x*Q1.z + w.y*Q1.w + w.z*Q2.x + w.w*Q2.y;
        a7 += w.x*Q1.w + w.y*Q2.x + w.z*Q2.y + w.w*Q2.z;
        Q0 = Q1; Q1 = Q2;
    }

    // replicate-pad corrections
    const float x0 = xr[0], xN = xr[IMW - 1];
    const f32x4* __restrict__ L4 = (const f32x4*)(ws + 128);
    const f32x4* __restrict__ R4 = (const f32x4*)(ws + 640);
    f32x4 La = L4[2*t], Lb = L4[2*t+1], Ra = R4[2*t], Rb = R4[2*t+1];
    a0 += x0*La.x + xN*Ra.x;  a1 += x0*La.y + xN*Ra.y;
    a2 += x0*La.z + xN*Ra.z;  a3 += x0*La.w + xN*Ra.w;
    a4 += x0*Lb.x + xN*Rb.x;  a5 += x0*Lb.y + xN*Rb.y;
    a6 += x0*Lb.z + xN*Rb.z;  a7 += x0*Lb.w + xN*Rb.w;

    // pack 8 fp32 -> 4 bf16-pair dwords (cols 8t..8t+7; lo = even col)
    u32x4 st;
    st.x = bf16pair(a0, a1);
    st.y = bf16pair(a2, a3);
    st.z = bf16pair(a4, a5);
    st.w = bf16pair(a6, a7);
    ((u32x4*)(tmpb + (size_t)row * IMW))[t] = st;   // 16B store, coalesced
}

// ---------------------------------------------------------------------------
// Kernel 3: vertical pass — round-7 proven body on bf16 tmp. Loads are b32
// (one bf16 col-pair), unpacked to fp32 (2 VALU) into the same f32x2 window;
// halves the 8.5x tmp re-read (204 -> 102 MB). SRD: voffL = colpair*4,
// soffset = row*1024 (SALU); rows <0/>511 -> HW zero-fill dword -> unpacks
// to 0.0 (zero-pad preserved). P0/P1 2-chunk prefetch kept. Output stays
// fp32 (b64 stores).
// Invariant at iter c: W[d]=row base+4c+d (d<19), P0[e]=+19+e, P1[e]=+23+e.
// ---------------------------------------------------------------------------
#define VR 16
__global__ __launch_bounds__(128) void vblur(const unsigned short* __restrict__ tmpb,
                                             const float* __restrict__ ws,
                                             float* __restrict__ out) {
    const int t     = threadIdx.x;                 // 0..127
    const int b     = blockIdx.x;                  // 0..1535
    const int half  = b & 1;                       // column half
    const int r0    = ((b >> 1) & 31) * VR;        // output rows r0..r0+15
    const int plane = b >> 6;
    const int base  = r0 - KMEAN;
    const int cp    = half * 128 + t;              // col-pair index 0..255
    const int voffL = cp * 4;                      // byte offset in bf16 row
    const int voffS = cp * 8;                      // byte offset in fp32 row

    const unsigned short* __restrict__ tp = tmpb + (size_t)plane * (IMW * IMH);
    float* __restrict__ op = out + (size_t)plane * (IMW * IMH);
    const i32x4 srdT = make_srd(tp, IMW * IMH * 2);   // bf16 plane buffer
    const i32x4 srdO = make_srd(op, IMW * IMH * 4);
    const f32x4* __restrict__ w4 = (const f32x4*)ws;

    f32x2 W[VR + 3];                               // rows base+4c .. base+4c+18
    #pragma unroll
    for (int d = 0; d < VR + 3; ++d)
        W[d] = bf16unpk(buf_load_u32(srdT, voffL, (base + d) * (IMW * 2), 0));
    unsigned P0[4], P1[4];                         // chunks c+1, c+2 in flight
    #pragma unroll
    for (int e = 0; e < 4; ++e)
        P0[e] = buf_load_u32(srdT, voffL, (base + 19 + e) * (IMW * 2), 0);
    #pragma unroll
    for (int e = 0; e < 4; ++e)
        P1[e] = buf_load_u32(srdT, voffL, (base + 23 + e) * (IMW * 2), 0);

    f32x2 acc[VR];
    #pragma unroll
    for (int i = 0; i < VR; ++i) { acc[i].x = 0.f; acc[i].y = 0.f; }

    #pragma unroll
    for (int c = 0; c < 31; ++c) {
        f32x4 w = w4[c];                           // uniform -> s_load
        #pragma unroll
        for (int s = 0; s < 4; ++s) {
            float wv = (s == 0) ? w.x : (s == 1) ? w.y : (s == 2) ? w.z : w.w;
            #pragma unroll
            for (int i = 0; i < VR; ++i) {
                acc[i].x = fmaf(wv, W[i + s].x, acc[i].x);
                acc[i].y = fmaf(wv, W[i + s].y, acc[i].y);
            }
        }
        if (c < 30) {
            #pragma unroll
            for (int d = 0; d < VR - 1; ++d) W[d] = W[d + 4];
            #pragma unroll
            for (int e = 0; e < 4; ++e) W[VR - 1 + e] = bf16unpk(P0[e]);
            #pragma unroll
            for (int e = 0; e < 4; ++e) P0[e] = P1[e];
            if (c < 28) {
                #pragma unroll
                for (int e = 0; e < 4; ++e)
                    P1[e] = buf_load_u32(srdT, voffL, (base + 4*c + 27 + e) * (IMW * 2), 0);
            }
        }
    }

    // replicate-pad corrections: rows 0 and 511, scalar weights L[r]/R[r]
    f32x2 T0 = bf16unpk(buf_load_u32(srdT, voffL, 0, 0));
    f32x2 TN = bf16unpk(buf_load_u32(srdT, voffL, (IMH - 1) * (IMW * 2), 0));
    const float* __restrict__ Lf = ws + 128;
    const float* __restrict__ Rf = ws + 640;
    #pragma unroll
    for (int i = 0; i < VR; ++i) {
        float L = Lf[r0 + i], R = Rf[r0 + i];      // uniform -> s_load
        acc[i].x += L * T0.x + R * TN.x;
        acc[i].y += L * T0.y + R * TN.y;
    }

    #pragma unroll
    for (int i = 0; i < VR; ++i)
        buf_store_x2(acc[i], srdO, voffS, (r0 + i) * (IMW * 4), 0);
}

// ---------------------------------------------------------------------------
extern "C" void kernel_launch(void* const* d_in, const int* in_sizes, int n_in,
                              void* d_out, int out_size, void* d_ws, size_t ws_size,
                              hipStream_t stream) {
    const float* x     = (const float*)d_in[0];
    const float* sigma = (const float*)d_in[1];
    float* out = (float*)d_out;

    // ws: [0,128) taps, [128,640) L, [640,1152) R (floats); bf16 tmp at byte 4608
    float* ws_f = (float*)d_ws;
    unsigned short* tmpb = (unsigned short*)((char*)d_ws + 4608);

    weights_kernel<<<1, 128, 0, stream>>>(sigma, ws_f);
    hblur<<<NPLANES * IMH / 4, 256, 0, stream>>>(x, ws_f, tmpb);
    vblur<<<NPLANES * (IMH / VR) * 2, 128, 0, stream>>>(tmpb, ws_f, out);
}